// Round 3
// baseline (154.309 us; speedup 1.0000x reference)
//
#include <hip/hip_runtime.h>
#include <math.h>

#define MARGIN 1.9f
#define NMAX 1024   // max rows supported by LDS layout (n=640 here)

// ---------------------------------------------------------------------------
// K1: fully fused per-anchor kernel. One block per anchor i.
//   dist phase: one WAVE per column j — 64 lanes cooperatively load row j
//   (coalesced float2), compute sum((e_i - e_j)^2) with a 6-step shuffle
//   reduce, lane 0 writes dist to LDS row[].
//   sweep phase: positives compacted to a small LDS list (~P atomics);
//   negatives held as 4 INF-padded registers per thread (no dynamic indexing,
//   no neg list). Per-block partials written to d_ws (no zeroing needed).
// ---------------------------------------------------------------------------
__global__ __launch_bounds__(256) void fused_triplet_kernel(
        const float* __restrict__ e, const int* __restrict__ lab,
        int n, int d,
        float* __restrict__ part_sum,          // [gridDim]
        unsigned int* __restrict__ part_ne,    // [gridDim]
        unsigned int* __restrict__ part_valid) // [gridDim]
{
    __shared__ float ei[512];          // d <= 1024 (d=128 here); float2-read
    __shared__ float row[NMAX];        // dist row i
    __shared__ float pos[NMAX];        // compacted positive distances
    __shared__ int   labs[NMAX];
    __shared__ int p_cnt, n_cnt;
    __shared__ float red_s[4];
    __shared__ unsigned int red_c[4];

    const int i    = blockIdx.x;
    const int tid  = threadIdx.x;
    const int lane = tid & 63;
    const int wv   = tid >> 6;

    if (tid == 0) { p_cnt = 0; n_cnt = 0; }
    for (int t = tid; t < d; t += blockDim.x) ei[t] = e[(size_t)i * d + t];
    for (int j = tid; j < n; j += blockDim.x) labs[j] = lab[j];
    __syncthreads();

    const int my_lab = labs[i];
    const int d2 = d >> 1;
    const float2* ei2 = (const float2*)ei;

    // ---- dist row: one wave per column, coalesced float2 loads ----
    for (int j = wv; j < n; j += 4) {
        const float2* rj = (const float2*)(e + (size_t)j * d);
        float v = 0.f;
        for (int t = lane; t < d2; t += 64) {        // d=128 -> 1 iteration
            float2 b = rj[t];
            float2 a = ei2[t];
            float dx = a.x - b.x, dy = a.y - b.y;
            v += dx * dx + dy * dy;
        }
        for (int off = 32; off > 0; off >>= 1) v += __shfl_down(v, off, 64);
        if (lane == 0) row[j] = (v == 0.f) ? 0.f : sqrtf(v);
    }
    __syncthreads();

    // ---- compact positives; count negatives ----
    int local_neg = 0;
    for (int j = tid; j < n; j += blockDim.x) {
        bool same = (labs[j] == my_lab);
        if (same) {
            if (j != i) { int k = atomicAdd(&p_cnt, 1); pos[k] = row[j]; }
        } else {
            local_neg++;
        }
    }
    for (int off = 32; off > 0; off >>= 1) local_neg += __shfl_down(local_neg, off, 64);
    if (lane == 0) atomicAdd(&n_cnt, local_neg);

    // ---- negatives as INF-padded registers (NMAX/256 = 4 slots) ----
    const float INF = __builtin_huge_valf();
    int j0 = tid, j1 = tid + 256, j2 = tid + 512, j3 = tid + 768;
    float n0 = (j0 < n && labs[j0] != my_lab) ? row[j0] : INF;
    float n1 = (j1 < n && labs[j1] != my_lab) ? row[j1] : INF;
    float n2 = (j2 < n && labs[j2] != my_lab) ? row[j2] : INF;
    float n3 = (j3 < n && labs[j3] != my_lab) ? row[j3] : INF;
    __syncthreads();
    const int P = p_cnt, N = n_cnt;

    // ---- sweep: serial over positives (LDS broadcast), 4 negs in regs ----
    float sum = 0.f;
    unsigned int c = 0;
    for (int j = 0; j < P; ++j) {
        float a = pos[j] + MARGIN;
        float t0 = a - n0; if (t0 > 0.f) { sum += t0; c++; }
        float t1 = a - n1; if (t1 > 0.f) { sum += t1; c++; }
        float t2 = a - n2; if (t2 > 0.f) { sum += t2; c++; }
        float t3 = a - n3; if (t3 > 0.f) { sum += t3; c++; }
    }

    // ---- block reduction ----
    for (int off = 32; off > 0; off >>= 1) {
        sum += __shfl_down(sum, off, 64);
        c   += __shfl_down(c,   off, 64);
    }
    if (lane == 0) { red_s[wv] = sum; red_c[wv] = c; }
    __syncthreads();
    if (tid == 0) {
        float s = 0.f; unsigned int cc = 0;
        for (int w = 0; w < 4; ++w) { s += red_s[w]; cc += red_c[w]; }
        part_sum[i]   = s;
        part_ne[i]    = cc;
        part_valid[i] = (unsigned int)P * (unsigned int)N;
    }
}

// ---------------------------------------------------------------------------
// K2: reduce 640 partials -> out[4] = {loss, num_valid, num_non_easy, frac}
// ---------------------------------------------------------------------------
__global__ __launch_bounds__(256) void finalize_kernel(
        const float* __restrict__ part_sum,
        const unsigned int* __restrict__ part_ne,
        const unsigned int* __restrict__ part_valid,
        int nblk, float* __restrict__ out)
{
    __shared__ float red_s[4];
    __shared__ unsigned long long red_ne[4], red_nv[4];
    int tid = threadIdx.x;

    float s = 0.f;
    unsigned long long ne = 0, nv = 0;
    for (int b = tid; b < nblk; b += blockDim.x) {
        s  += part_sum[b];
        ne += part_ne[b];
        nv += part_valid[b];
    }
    for (int off = 32; off > 0; off >>= 1) {
        s  += __shfl_down(s,  off, 64);
        ne += __shfl_down(ne, off, 64);
        nv += __shfl_down(nv, off, 64);
    }
    int wave = tid >> 6;
    if ((tid & 63) == 0) { red_s[wave] = s; red_ne[wave] = ne; red_nv[wave] = nv; }
    __syncthreads();
    if (tid == 0) {
        float ts = 0.f; unsigned long long tne = 0, tnv = 0;
        int nwaves = (blockDim.x + 63) >> 6;
        for (int w = 0; w < nwaves; ++w) { ts += red_s[w]; tne += red_ne[w]; tnv += red_nv[w]; }
        float fne = (float)tne;
        float fnv = (float)tnv;
        out[0] = (fne > 0.f) ? (ts / fmaxf(fne, 1.f)) : 0.f;
        out[1] = fnv;
        out[2] = fne;
        out[3] = fne / (fnv + 1e-16f);
    }
}

extern "C" void kernel_launch(void* const* d_in, const int* in_sizes, int n_in,
                              void* d_out, int out_size, void* d_ws, size_t ws_size,
                              hipStream_t stream) {
    const float* e  = (const float*)d_in[0];
    const int* lab  = (const int*)d_in[1];
    int n = in_sizes[1];           // 640
    int d = in_sizes[0] / n;       // 128

    // per-block partials in workspace (written before read; no zeroing needed)
    char* ws = (char*)d_ws;
    float*        part_sum   = (float*)ws;
    unsigned int* part_ne    = (unsigned int*)(ws + (size_t)n * 4);
    unsigned int* part_valid = (unsigned int*)(ws + (size_t)n * 8);

    fused_triplet_kernel<<<n, 256, 0, stream>>>(e, lab, n, d,
                                                part_sum, part_ne, part_valid);
    finalize_kernel<<<1, 256, 0, stream>>>(part_sum, part_ne, part_valid,
                                           n, (float*)d_out);
}

// Round 4
// 99.093 us; speedup vs baseline: 1.5572x; 1.5572x over previous
//
#include <hip/hip_runtime.h>
#include <math.h>

#define MARGIN 1.9f
#define TILE 32
#define NMAX 1024   // max n supported by K2's LDS layout (n=640 here)

// ---------------------------------------------------------------------------
// K1: pairwise distance matrix via LDS-tiled "GEMM" on sum((a-b)^2).
// Grid (n/32, n/32), block 256 = 16x16 threads, each computes 2x2 outputs
// at (ty,tx), (ty,tx+16), (ty+16,tx), (ty+16,tx+16) within the 32x32 tile.
// LDS rows padded to 33 float4 (132 floats) -> A reads broadcast, B reads
// 2-way (free). Block (0,0) also zeroes the global accumulators for K2.
// ---------------------------------------------------------------------------
__global__ __launch_bounds__(256) void dist_kernel(
        const float* __restrict__ e, int n, int d,
        float* __restrict__ dist,
        float* __restrict__ total,
        unsigned long long* __restrict__ cnt_ne,
        unsigned long long* __restrict__ cnt_valid,
        unsigned int* __restrict__ ticket)
{
    if (blockIdx.x == 0 && blockIdx.y == 0 && threadIdx.x == 0) {
        *total = 0.f; *cnt_ne = 0ull; *cnt_valid = 0ull; *ticket = 0u;
    }
    __shared__ float As[TILE * 132];
    __shared__ float Bs[TILE * 132];
    const int tid  = threadIdx.x;
    const int row0 = blockIdx.y * TILE;
    const int col0 = blockIdx.x * TILE;
    const int nf4  = d >> 2;                    // float4s per row (32)

    const float4* eg  = (const float4*)e;
    float4* As4 = (float4*)As;
    float4* Bs4 = (float4*)Bs;
    for (int f = tid; f < TILE * nf4; f += 256) {
        int r = f / nf4, c = f - r * nf4;
        int ga = row0 + r; if (ga >= n) ga = n - 1;   // clamp (n%32==0 here)
        int gb = col0 + r; if (gb >= n) gb = n - 1;
        As4[r * 33 + c] = eg[(size_t)ga * nf4 + c];
        Bs4[r * 33 + c] = eg[(size_t)gb * nf4 + c];
    }
    __syncthreads();

    const int tx = tid & 15, ty = tid >> 4;
    float a00 = 0.f, a01 = 0.f, a10 = 0.f, a11 = 0.f;
    for (int t = 0; t < nf4; ++t) {
        float4 A0 = As4[ty * 33 + t];
        float4 A1 = As4[(ty + 16) * 33 + t];
        float4 B0 = Bs4[tx * 33 + t];
        float4 B1 = Bs4[(tx + 16) * 33 + t];
        float dx;
#define ACC(acc, A, B, comp) dx = A.comp - B.comp; acc = fmaf(dx, dx, acc)
        ACC(a00, A0, B0, x); ACC(a00, A0, B0, y); ACC(a00, A0, B0, z); ACC(a00, A0, B0, w);
        ACC(a01, A0, B1, x); ACC(a01, A0, B1, y); ACC(a01, A0, B1, z); ACC(a01, A0, B1, w);
        ACC(a10, A1, B0, x); ACC(a10, A1, B0, y); ACC(a10, A1, B0, z); ACC(a10, A1, B0, w);
        ACC(a11, A1, B1, x); ACC(a11, A1, B1, y); ACC(a11, A1, B1, z); ACC(a11, A1, B1, w);
#undef ACC
    }

    const int r0 = row0 + ty, r1 = row0 + ty + 16;
    const int c0 = col0 + tx, c1 = col0 + tx + 16;
#define EMIT(rr, cc, acc) if ((rr) < n && (cc) < n) \
        dist[(size_t)(rr) * n + (cc)] = ((acc) == 0.f) ? 0.f : sqrtf(acc)
    EMIT(r0, c0, a00); EMIT(r0, c1, a01);
    EMIT(r1, c0, a10); EMIT(r1, c1, a11);
#undef EMIT
}

// ---------------------------------------------------------------------------
// K2: per-anchor triplet sweep + last-block finalize. One block per anchor i.
// Reads dist row i (coalesced, L2-hit). Positives compacted to LDS list;
// negatives held as 4 INF-padded registers. Block partials accumulated with
// device atomics; the last block (ticket) computes the 4 outputs.
// ---------------------------------------------------------------------------
__global__ __launch_bounds__(256) void triplet_kernel(
        const float* __restrict__ dist, const int* __restrict__ lab, int n,
        float* __restrict__ total,
        unsigned long long* __restrict__ cnt_ne,
        unsigned long long* __restrict__ cnt_valid,
        unsigned int* __restrict__ ticket,
        float* __restrict__ out)
{
    __shared__ float row[NMAX];
    __shared__ float pos[NMAX];
    __shared__ int   labs[NMAX];
    __shared__ int p_cnt, n_cnt;
    __shared__ float red_s[4];
    __shared__ unsigned int red_c[4];

    const int i    = blockIdx.x;
    const int tid  = threadIdx.x;
    const int lane = tid & 63;
    const int wv   = tid >> 6;

    if (tid == 0) { p_cnt = 0; n_cnt = 0; }
    for (int j = tid; j < n; j += 256) {
        row[j]  = dist[(size_t)i * n + j];
        labs[j] = lab[j];
    }
    __syncthreads();

    const int my_lab = labs[i];
    int local_neg = 0;
    for (int j = tid; j < n; j += 256) {
        if (labs[j] == my_lab) {
            if (j != i) { int k = atomicAdd(&p_cnt, 1); pos[k] = row[j]; }
        } else {
            local_neg++;
        }
    }
    for (int off = 32; off > 0; off >>= 1) local_neg += __shfl_down(local_neg, off, 64);
    if (lane == 0) atomicAdd(&n_cnt, local_neg);

    // negatives as INF-padded registers (NMAX/256 = 4 slots)
    const float INF = __builtin_huge_valf();
    int j0 = tid, j1 = tid + 256, j2 = tid + 512, j3 = tid + 768;
    float n0 = (j0 < n && labs[j0] != my_lab) ? row[j0] : INF;
    float n1 = (j1 < n && labs[j1] != my_lab) ? row[j1] : INF;
    float n2 = (j2 < n && labs[j2] != my_lab) ? row[j2] : INF;
    float n3 = (j3 < n && labs[j3] != my_lab) ? row[j3] : INF;
    __syncthreads();
    const int P = p_cnt, N = n_cnt;

    float sum = 0.f;
    unsigned int c = 0;
    for (int j = 0; j < P; ++j) {
        float a = pos[j] + MARGIN;        // LDS broadcast
        float t0 = a - n0; if (t0 > 0.f) { sum += t0; c++; }
        float t1 = a - n1; if (t1 > 0.f) { sum += t1; c++; }
        float t2 = a - n2; if (t2 > 0.f) { sum += t2; c++; }
        float t3 = a - n3; if (t3 > 0.f) { sum += t3; c++; }
    }

    for (int off = 32; off > 0; off >>= 1) {
        sum += __shfl_down(sum, off, 64);
        c   += __shfl_down(c,   off, 64);
    }
    if (lane == 0) { red_s[wv] = sum; red_c[wv] = c; }
    __syncthreads();

    if (tid == 0) {
        float s = 0.f; unsigned int cc = 0;
        for (int w = 0; w < 4; ++w) { s += red_s[w]; cc += red_c[w]; }
        atomicAdd(total, s);
        atomicAdd(cnt_ne, (unsigned long long)cc);
        atomicAdd(cnt_valid, (unsigned long long)P * (unsigned long long)N);
        __threadfence();
        unsigned int t = atomicAdd(ticket, 1u);
        if (t == (unsigned int)(gridDim.x - 1)) {
            // last block: all other blocks' accumulator RMWs are visible
            float ts               = atomicAdd(total, 0.f);
            unsigned long long tne = atomicAdd(cnt_ne, 0ull);
            unsigned long long tnv = atomicAdd(cnt_valid, 0ull);
            float fne = (float)tne;
            float fnv = (float)tnv;
            out[0] = (fne > 0.f) ? (ts / fmaxf(fne, 1.f)) : 0.f;
            out[1] = fnv;
            out[2] = fne;
            out[3] = fne / (fnv + 1e-16f);
        }
    }
}

extern "C" void kernel_launch(void* const* d_in, const int* in_sizes, int n_in,
                              void* d_out, int out_size, void* d_ws, size_t ws_size,
                              hipStream_t stream) {
    const float* e  = (const float*)d_in[0];
    const int* lab  = (const int*)d_in[1];
    int n = in_sizes[1];           // 640
    int d = in_sizes[0] / n;       // 128

    // ws layout: [0] float total | [8] ull cnt_ne | [16] ull cnt_valid
    //            [24] uint ticket | [64..] dist matrix n*n floats
    char* ws = (char*)d_ws;
    float*              total     = (float*)ws;
    unsigned long long* cnt_ne    = (unsigned long long*)(ws + 8);
    unsigned long long* cnt_valid = (unsigned long long*)(ws + 16);
    unsigned int*       ticket    = (unsigned int*)(ws + 24);
    float*              dist      = (float*)(ws + 64);

    int nt = (n + TILE - 1) / TILE;   // 20
    dim3 grid(nt, nt);
    dist_kernel<<<grid, 256, 0, stream>>>(e, n, d, dist,
                                          total, cnt_ne, cnt_valid, ticket);
    triplet_kernel<<<n, 256, 0, stream>>>(dist, lab, n,
                                          total, cnt_ne, cnt_valid, ticket,
                                          (float*)d_out);
}

// Round 5
// 88.058 us; speedup vs baseline: 1.7524x; 1.1253x over previous
//
#include <hip/hip_runtime.h>
#include <math.h>

#define MARGIN 1.9f
#define TILE 32
#define NMAX 1024   // max n supported by K2's LDS layout (n=640 here)

// ---------------------------------------------------------------------------
// K1: pairwise distance matrix via LDS-tiled "GEMM" on sum((a-b)^2).
// Grid (n/32, n/32), block 256 = 16x16 threads, each computes 2x2 outputs.
// LDS rows padded to 33 float4 -> A reads broadcast, B reads 2-way (free).
// Block (0,0) zeroes the ticket counter for K2.
// ---------------------------------------------------------------------------
__global__ __launch_bounds__(256) void dist_kernel(
        const float* __restrict__ e, int n, int d,
        float* __restrict__ dist,
        unsigned int* __restrict__ ticket)
{
    if (blockIdx.x == 0 && blockIdx.y == 0 && threadIdx.x == 0) {
        __hip_atomic_store(ticket, 0u, __ATOMIC_RELAXED, __HIP_MEMORY_SCOPE_AGENT);
    }
    __shared__ float As[TILE * 132];
    __shared__ float Bs[TILE * 132];
    const int tid  = threadIdx.x;
    const int row0 = blockIdx.y * TILE;
    const int col0 = blockIdx.x * TILE;
    const int nf4  = d >> 2;                    // float4s per row (32)

    const float4* eg  = (const float4*)e;
    float4* As4 = (float4*)As;
    float4* Bs4 = (float4*)Bs;
    for (int f = tid; f < TILE * nf4; f += 256) {
        int r = f / nf4, c = f - r * nf4;
        int ga = row0 + r; if (ga >= n) ga = n - 1;   // clamp (n%32==0 here)
        int gb = col0 + r; if (gb >= n) gb = n - 1;
        As4[r * 33 + c] = eg[(size_t)ga * nf4 + c];
        Bs4[r * 33 + c] = eg[(size_t)gb * nf4 + c];
    }
    __syncthreads();

    const int tx = tid & 15, ty = tid >> 4;
    float a00 = 0.f, a01 = 0.f, a10 = 0.f, a11 = 0.f;
    for (int t = 0; t < nf4; ++t) {
        float4 A0 = As4[ty * 33 + t];
        float4 A1 = As4[(ty + 16) * 33 + t];
        float4 B0 = Bs4[tx * 33 + t];
        float4 B1 = Bs4[(tx + 16) * 33 + t];
        float dx;
#define ACC(acc, A, B, comp) dx = A.comp - B.comp; acc = fmaf(dx, dx, acc)
        ACC(a00, A0, B0, x); ACC(a00, A0, B0, y); ACC(a00, A0, B0, z); ACC(a00, A0, B0, w);
        ACC(a01, A0, B1, x); ACC(a01, A0, B1, y); ACC(a01, A0, B1, z); ACC(a01, A0, B1, w);
        ACC(a10, A1, B0, x); ACC(a10, A1, B0, y); ACC(a10, A1, B0, z); ACC(a10, A1, B0, w);
        ACC(a11, A1, B1, x); ACC(a11, A1, B1, y); ACC(a11, A1, B1, z); ACC(a11, A1, B1, w);
#undef ACC
    }

    const int r0 = row0 + ty, r1 = row0 + ty + 16;
    const int c0 = col0 + tx, c1 = col0 + tx + 16;
#define EMIT(rr, cc, acc) if ((rr) < n && (cc) < n) \
        dist[(size_t)(rr) * n + (cc)] = ((acc) == 0.f) ? 0.f : sqrtf(acc)
    EMIT(r0, c0, a00); EMIT(r0, c1, a01);
    EMIT(r1, c0, a10); EMIT(r1, c1, a11);
#undef EMIT
}

// ---------------------------------------------------------------------------
// K2: per-anchor triplet sweep. One block per anchor i.
// Per-block partials -> DISTINCT addresses (no contended atomics). One
// relaxed agent-scope ticket fetch_add per block; the last block reduces the
// 640 partials with agent-scope loads and writes the 4 outputs.
// ---------------------------------------------------------------------------
__global__ __launch_bounds__(256) void triplet_kernel(
        const float* __restrict__ dist, const int* __restrict__ lab, int n,
        float* __restrict__ part_sum,          // [gridDim]
        unsigned int* __restrict__ part_ne,    // [gridDim]
        unsigned int* __restrict__ part_valid, // [gridDim]
        unsigned int* __restrict__ ticket,
        float* __restrict__ out)
{
    __shared__ float row[NMAX];
    __shared__ float pos[NMAX];
    __shared__ int   labs[NMAX];
    __shared__ int p_cnt, n_cnt;
    __shared__ float red_s[4];
    __shared__ unsigned int red_c[4];
    __shared__ int is_last;

    const int i    = blockIdx.x;
    const int tid  = threadIdx.x;
    const int lane = tid & 63;
    const int wv   = tid >> 6;

    if (tid == 0) { p_cnt = 0; n_cnt = 0; }
    for (int j = tid; j < n; j += 256) {
        row[j]  = dist[(size_t)i * n + j];
        labs[j] = lab[j];
    }
    __syncthreads();

    const int my_lab = labs[i];
    int local_neg = 0;
    for (int j = tid; j < n; j += 256) {
        if (labs[j] == my_lab) {
            if (j != i) { int k = atomicAdd(&p_cnt, 1); pos[k] = row[j]; }
        } else {
            local_neg++;
        }
    }
    for (int off = 32; off > 0; off >>= 1) local_neg += __shfl_down(local_neg, off, 64);
    if (lane == 0) atomicAdd(&n_cnt, local_neg);

    // negatives as INF-padded registers (NMAX/256 = 4 slots)
    const float INF = __builtin_huge_valf();
    int j0 = tid, j1 = tid + 256, j2 = tid + 512, j3 = tid + 768;
    float n0 = (j0 < n && labs[j0] != my_lab) ? row[j0] : INF;
    float n1 = (j1 < n && labs[j1] != my_lab) ? row[j1] : INF;
    float n2 = (j2 < n && labs[j2] != my_lab) ? row[j2] : INF;
    float n3 = (j3 < n && labs[j3] != my_lab) ? row[j3] : INF;
    __syncthreads();
    const int P = p_cnt, N = n_cnt;

    float sum = 0.f;
    unsigned int c = 0;
    for (int j = 0; j < P; ++j) {
        float a = pos[j] + MARGIN;        // LDS broadcast
        float t0 = a - n0; if (t0 > 0.f) { sum += t0; c++; }
        float t1 = a - n1; if (t1 > 0.f) { sum += t1; c++; }
        float t2 = a - n2; if (t2 > 0.f) { sum += t2; c++; }
        float t3 = a - n3; if (t3 > 0.f) { sum += t3; c++; }
    }

    for (int off = 32; off > 0; off >>= 1) {
        sum += __shfl_down(sum, off, 64);
        c   += __shfl_down(c,   off, 64);
    }
    if (lane == 0) { red_s[wv] = sum; red_c[wv] = c; }
    __syncthreads();

    if (tid == 0) {
        float s = 0.f; unsigned int cc = 0;
        for (int w = 0; w < 4; ++w) { s += red_s[w]; cc += red_c[w]; }
        // distinct-address partials, agent scope (bypass non-coherent caches)
        __hip_atomic_store(&part_sum[i], s, __ATOMIC_RELAXED, __HIP_MEMORY_SCOPE_AGENT);
        __hip_atomic_store(&part_ne[i], cc, __ATOMIC_RELAXED, __HIP_MEMORY_SCOPE_AGENT);
        __hip_atomic_store(&part_valid[i], (unsigned int)P * (unsigned int)N,
                           __ATOMIC_RELAXED, __HIP_MEMORY_SCOPE_AGENT);
        __threadfence();   // release: partials visible before ticket bump
        unsigned int t = __hip_atomic_fetch_add(ticket, 1u, __ATOMIC_ACQ_REL,
                                                __HIP_MEMORY_SCOPE_AGENT);
        is_last = (t == (unsigned int)(gridDim.x - 1)) ? 1 : 0;
    }
    __syncthreads();

    if (is_last) {
        // last block: reduce all per-block partials (distinct lines, pipelined)
        __threadfence();   // acquire
        float s = 0.f;
        unsigned long long ne = 0, nv = 0;
        int nblk = gridDim.x;
        for (int b = tid; b < nblk; b += 256) {
            s  += __hip_atomic_load(&part_sum[b],   __ATOMIC_RELAXED, __HIP_MEMORY_SCOPE_AGENT);
            ne += __hip_atomic_load(&part_ne[b],    __ATOMIC_RELAXED, __HIP_MEMORY_SCOPE_AGENT);
            nv += __hip_atomic_load(&part_valid[b], __ATOMIC_RELAXED, __HIP_MEMORY_SCOPE_AGENT);
        }
        for (int off = 32; off > 0; off >>= 1) {
            s  += __shfl_down(s,  off, 64);
            ne += __shfl_down(ne, off, 64);
            nv += __shfl_down(nv, off, 64);
        }
        __shared__ float fr_s[4];
        __shared__ unsigned long long fr_ne[4], fr_nv[4];
        if (lane == 0) { fr_s[wv] = s; fr_ne[wv] = ne; fr_nv[wv] = nv; }
        __syncthreads();
        if (tid == 0) {
            float ts = 0.f; unsigned long long tne = 0, tnv = 0;
            for (int w = 0; w < 4; ++w) { ts += fr_s[w]; tne += fr_ne[w]; tnv += fr_nv[w]; }
            float fne = (float)tne;
            float fnv = (float)tnv;
            out[0] = (fne > 0.f) ? (ts / fmaxf(fne, 1.f)) : 0.f;
            out[1] = fnv;
            out[2] = fne;
            out[3] = fne / (fnv + 1e-16f);
        }
    }
}

extern "C" void kernel_launch(void* const* d_in, const int* in_sizes, int n_in,
                              void* d_out, int out_size, void* d_ws, size_t ws_size,
                              hipStream_t stream) {
    const float* e  = (const float*)d_in[0];
    const int* lab  = (const int*)d_in[1];
    int n = in_sizes[1];           // 640
    int d = in_sizes[0] / n;       // 128

    // ws layout: [0] uint ticket (own line) | [256..] per-block partials
    //            (3 arrays of n) | then dist matrix n*n floats
    char* ws = (char*)d_ws;
    unsigned int* ticket     = (unsigned int*)ws;
    float*        part_sum   = (float*)(ws + 256);
    unsigned int* part_ne    = (unsigned int*)(ws + 256 + (size_t)n * 4);
    unsigned int* part_valid = (unsigned int*)(ws + 256 + (size_t)n * 8);
    size_t dist_off = (256 + (size_t)n * 12 + 255) & ~(size_t)255;
    float*        dist       = (float*)(ws + dist_off);

    int nt = (n + TILE - 1) / TILE;   // 20
    dim3 grid(nt, nt);
    dist_kernel<<<grid, 256, 0, stream>>>(e, n, d, dist, ticket);
    triplet_kernel<<<n, 256, 0, stream>>>(dist, lab, n,
                                          part_sum, part_ne, part_valid,
                                          ticket, (float*)d_out);
}

// Round 6
// 73.691 us; speedup vs baseline: 2.0940x; 1.1950x over previous
//
#include <hip/hip_runtime.h>
#include <math.h>

#define MARGIN 1.9f
#define TILE 32
#define NMAX 1024   // max n supported by K2's LDS layout (n=640 here)

// ---------------------------------------------------------------------------
// K1: pairwise distance matrix via LDS-tiled "GEMM" on sum((a-b)^2).
// Grid (n/32, n/32), block 256 = 16x16 threads, each computes 2x2 outputs.
// LDS rows padded to 33 float4 -> A reads broadcast, B reads 2-way (free).
// ---------------------------------------------------------------------------
__global__ __launch_bounds__(256) void dist_kernel(
        const float* __restrict__ e, int n, int d,
        float* __restrict__ dist)
{
    __shared__ float As[TILE * 132];
    __shared__ float Bs[TILE * 132];
    const int tid  = threadIdx.x;
    const int row0 = blockIdx.y * TILE;
    const int col0 = blockIdx.x * TILE;
    const int nf4  = d >> 2;                    // float4s per row (32)

    const float4* eg  = (const float4*)e;
    float4* As4 = (float4*)As;
    float4* Bs4 = (float4*)Bs;
    for (int f = tid; f < TILE * nf4; f += 256) {
        int r = f / nf4, c = f - r * nf4;
        int ga = row0 + r; if (ga >= n) ga = n - 1;   // clamp (n%32==0 here)
        int gb = col0 + r; if (gb >= n) gb = n - 1;
        As4[r * 33 + c] = eg[(size_t)ga * nf4 + c];
        Bs4[r * 33 + c] = eg[(size_t)gb * nf4 + c];
    }
    __syncthreads();

    const int tx = tid & 15, ty = tid >> 4;
    float a00 = 0.f, a01 = 0.f, a10 = 0.f, a11 = 0.f;
    for (int t = 0; t < nf4; ++t) {
        float4 A0 = As4[ty * 33 + t];
        float4 A1 = As4[(ty + 16) * 33 + t];
        float4 B0 = Bs4[tx * 33 + t];
        float4 B1 = Bs4[(tx + 16) * 33 + t];
        float dx;
#define ACC(acc, A, B, comp) dx = A.comp - B.comp; acc = fmaf(dx, dx, acc)
        ACC(a00, A0, B0, x); ACC(a00, A0, B0, y); ACC(a00, A0, B0, z); ACC(a00, A0, B0, w);
        ACC(a01, A0, B1, x); ACC(a01, A0, B1, y); ACC(a01, A0, B1, z); ACC(a01, A0, B1, w);
        ACC(a10, A1, B0, x); ACC(a10, A1, B0, y); ACC(a10, A1, B0, z); ACC(a10, A1, B0, w);
        ACC(a11, A1, B1, x); ACC(a11, A1, B1, y); ACC(a11, A1, B1, z); ACC(a11, A1, B1, w);
#undef ACC
    }

    const int r0 = row0 + ty, r1 = row0 + ty + 16;
    const int c0 = col0 + tx, c1 = col0 + tx + 16;
#define EMIT(rr, cc, acc) if ((rr) < n && (cc) < n) \
        dist[(size_t)(rr) * n + (cc)] = ((acc) == 0.f) ? 0.f : sqrtf(acc)
    EMIT(r0, c0, a00); EMIT(r0, c1, a01);
    EMIT(r1, c0, a10); EMIT(r1, c1, a11);
#undef EMIT
}

// ---------------------------------------------------------------------------
// K2: per-anchor triplet sweep. One block per anchor i. Plain stores of
// per-block partials to DISTINCT addresses — no atomics, no fences, no
// ticket. Visibility to K3 is provided by the inter-dispatch barrier
// (release at K2 end / acquire at K3 start, once per dispatch).
// ---------------------------------------------------------------------------
__global__ __launch_bounds__(256) void triplet_kernel(
        const float* __restrict__ dist, const int* __restrict__ lab, int n,
        float* __restrict__ part_sum,          // [gridDim]
        unsigned int* __restrict__ part_ne,    // [gridDim]
        unsigned int* __restrict__ part_valid) // [gridDim]
{
    __shared__ float row[NMAX];
    __shared__ float pos[NMAX];
    __shared__ int   labs[NMAX];
    __shared__ int p_cnt, n_cnt;
    __shared__ float red_s[4];
    __shared__ unsigned int red_c[4];

    const int i    = blockIdx.x;
    const int tid  = threadIdx.x;
    const int lane = tid & 63;
    const int wv   = tid >> 6;

    if (tid == 0) { p_cnt = 0; n_cnt = 0; }
    for (int j = tid; j < n; j += 256) {
        row[j]  = dist[(size_t)i * n + j];
        labs[j] = lab[j];
    }
    __syncthreads();

    const int my_lab = labs[i];
    int local_neg = 0;
    for (int j = tid; j < n; j += 256) {
        if (labs[j] == my_lab) {
            if (j != i) { int k = atomicAdd(&p_cnt, 1); pos[k] = row[j]; }
        } else {
            local_neg++;
        }
    }
    for (int off = 32; off > 0; off >>= 1) local_neg += __shfl_down(local_neg, off, 64);
    if (lane == 0) atomicAdd(&n_cnt, local_neg);

    // negatives as INF-padded registers (NMAX/256 = 4 slots)
    const float INF = __builtin_huge_valf();
    int j0 = tid, j1 = tid + 256, j2 = tid + 512, j3 = tid + 768;
    float n0 = (j0 < n && labs[j0] != my_lab) ? row[j0] : INF;
    float n1 = (j1 < n && labs[j1] != my_lab) ? row[j1] : INF;
    float n2 = (j2 < n && labs[j2] != my_lab) ? row[j2] : INF;
    float n3 = (j3 < n && labs[j3] != my_lab) ? row[j3] : INF;
    __syncthreads();
    const int P = p_cnt, N = n_cnt;

    float sum = 0.f;
    unsigned int c = 0;
    for (int j = 0; j < P; ++j) {
        float a = pos[j] + MARGIN;        // LDS broadcast
        float t0 = a - n0; if (t0 > 0.f) { sum += t0; c++; }
        float t1 = a - n1; if (t1 > 0.f) { sum += t1; c++; }
        float t2 = a - n2; if (t2 > 0.f) { sum += t2; c++; }
        float t3 = a - n3; if (t3 > 0.f) { sum += t3; c++; }
    }

    for (int off = 32; off > 0; off >>= 1) {
        sum += __shfl_down(sum, off, 64);
        c   += __shfl_down(c,   off, 64);
    }
    if (lane == 0) { red_s[wv] = sum; red_c[wv] = c; }
    __syncthreads();

    if (tid == 0) {
        float s = 0.f; unsigned int cc = 0;
        for (int w = 0; w < 4; ++w) { s += red_s[w]; cc += red_c[w]; }
        part_sum[i]   = s;
        part_ne[i]    = cc;
        part_valid[i] = (unsigned int)P * (unsigned int)N;
    }
}

// ---------------------------------------------------------------------------
// K3: reduce 640 partials -> out[4] = {loss, num_valid, num_non_easy, frac}
// ---------------------------------------------------------------------------
__global__ __launch_bounds__(256) void finalize_kernel(
        const float* __restrict__ part_sum,
        const unsigned int* __restrict__ part_ne,
        const unsigned int* __restrict__ part_valid,
        int nblk, float* __restrict__ out)
{
    __shared__ float red_s[4];
    __shared__ unsigned long long red_ne[4], red_nv[4];
    int tid = threadIdx.x;

    float s = 0.f;
    unsigned long long ne = 0, nv = 0;
    for (int b = tid; b < nblk; b += blockDim.x) {
        s  += part_sum[b];
        ne += part_ne[b];
        nv += part_valid[b];
    }
    for (int off = 32; off > 0; off >>= 1) {
        s  += __shfl_down(s,  off, 64);
        ne += __shfl_down(ne, off, 64);
        nv += __shfl_down(nv, off, 64);
    }
    int wave = tid >> 6;
    if ((tid & 63) == 0) { red_s[wave] = s; red_ne[wave] = ne; red_nv[wave] = nv; }
    __syncthreads();
    if (tid == 0) {
        float ts = 0.f; unsigned long long tne = 0, tnv = 0;
        int nwaves = (blockDim.x + 63) >> 6;
        for (int w = 0; w < nwaves; ++w) { ts += red_s[w]; tne += red_ne[w]; tnv += red_nv[w]; }
        float fne = (float)tne;
        float fnv = (float)tnv;
        out[0] = (fne > 0.f) ? (ts / fmaxf(fne, 1.f)) : 0.f;
        out[1] = fnv;
        out[2] = fne;
        out[3] = fne / (fnv + 1e-16f);
    }
}

extern "C" void kernel_launch(void* const* d_in, const int* in_sizes, int n_in,
                              void* d_out, int out_size, void* d_ws, size_t ws_size,
                              hipStream_t stream) {
    const float* e  = (const float*)d_in[0];
    const int* lab  = (const int*)d_in[1];
    int n = in_sizes[1];           // 640
    int d = in_sizes[0] / n;       // 128

    // ws layout: [0..] per-block partials (3 arrays of n) | then dist (n*n)
    char* ws = (char*)d_ws;
    float*        part_sum   = (float*)ws;
    unsigned int* part_ne    = (unsigned int*)(ws + (size_t)n * 4);
    unsigned int* part_valid = (unsigned int*)(ws + (size_t)n * 8);
    size_t dist_off = ((size_t)n * 12 + 255) & ~(size_t)255;
    float*        dist       = (float*)(ws + dist_off);

    int nt = (n + TILE - 1) / TILE;   // 20
    dim3 grid(nt, nt);
    dist_kernel<<<grid, 256, 0, stream>>>(e, n, d, dist);
    triplet_kernel<<<n, 256, 0, stream>>>(dist, lab, n,
                                          part_sum, part_ne, part_valid);
    finalize_kernel<<<1, 256, 0, stream>>>(part_sum, part_ne, part_valid,
                                           n, (float*)d_out);
}